// Round 4
// baseline (705.532 us; speedup 1.0000x reference)
//
#include <hip/hip_runtime.h>

#define TOKENS 2048
#define HIDDEN 2048
#define INTER  768
#define NEXP   16
#define NA     (TOKENS * 2)
#define MTILE  128
#define MAXT   64

typedef unsigned int   uint32;
typedef unsigned short u16;
typedef __bf16 bf16x8 __attribute__((ext_vector_type(8)));
typedef float  f32x4  __attribute__((ext_vector_type(4)));

__device__ __forceinline__ u16 f2bf(float f) {
    union { float f; uint32 u; } v; v.f = f;
    return (u16)((v.u + 0x7fffu + ((v.u >> 16) & 1u)) >> 16);
}
// fast pack of two fp32 -> two bf16 (round-half-away; plenty for 2% threshold)
__device__ __forceinline__ uint32 pk2(float a, float b) {
    union { float f; uint32 u; } x, y; x.f = a; y.f = b;
    return ((x.u + 0x8000u) >> 16) | ((y.u + 0x8000u) & 0xffff0000u);
}
__device__ __forceinline__ uint4 cvt8f(float4 a, float4 b) {
    uint4 o;
    o.x = pk2(a.x, a.y); o.y = pk2(a.z, a.w);
    o.z = pk2(b.x, b.y); o.w = pk2(b.z, b.w);
    return o;
}
// 16B-unit index into a row-major (rowstride 64 bf16) LDS tile, XOR-swizzled
__device__ __forceinline__ int swz(int row, int k8) { return row * 8 + (k8 ^ (row & 7)); }

__device__ __forceinline__ f32x4 mfma16(bf16x8 a, bf16x8 b, f32x4 c) {
    return __builtin_amdgcn_mfma_f32_16x16x32_bf16(a, b, c, 0, 0, 0);
}

// ---------------- X: fp32 -> bf16 once ----------------
__global__ void xcvt_kernel(const float* __restrict__ X, u16* __restrict__ Xb) {
    const int gid = blockIdx.x * 256 + threadIdx.x;
    const float4* s = (const float4*)X + (size_t)gid * 2;
    ((uint4*)Xb)[gid] = cvt8f(s[0], s[1]);
}

// ---------------- routing: bucket assignments, emit m-tile list ----------------
__global__ void route_kernel(const int* __restrict__ idx, int* __restrict__ meta,
                             int* __restrict__ bucket) {
    __shared__ int scnt[NEXP];
    __shared__ int soff[NEXP + 1];
    __shared__ int sfill[NEXP];
    __shared__ int sflag;
    const int tid = threadIdx.x;
    if (tid < NEXP) { scnt[tid] = 0; sfill[tid] = 0; }
    if (tid == 0) sflag = 0;
    __syncthreads();
    // int64-vs-int32 probe: int64 buffer has all-zero odd words
    int any = 0;
    for (int a = tid; a < NA / 2; a += 256) any |= idx[2 * a + 1];
    if (any) atomicOr(&sflag, 1);
    __syncthreads();
    const int stride = sflag ? 1 : 2;
    for (int a = tid; a < NA; a += 256) atomicAdd(&scnt[idx[a * stride]], 1);
    __syncthreads();
    if (tid == 0) {
        int s = 0;
        for (int e = 0; e < NEXP; ++e) { soff[e] = s; s += scnt[e]; }
        soff[NEXP] = s;
        int nt = 0;
        for (int e = 0; e < NEXP; ++e) {
            const int ne = soff[e + 1] - soff[e];
            for (int m0 = 0; m0 < ne; m0 += MTILE) {
                meta[32 + nt] = e;      // tile expert
                meta[96 + nt] = m0;     // tile m0
                ++nt;
            }
        }
        meta[17] = nt;
    }
    __syncthreads();
    for (int a = tid; a < NA; a += 256) {
        int e = idx[a * stride];
        int slot = atomicAdd(&sfill[e], 1);
        bucket[soff[e] + slot] = a;   // assignment id; token = a>>1
    }
    if (tid <= NEXP) meta[tid] = soff[tid];
}

// ================= GEMM1 pipeline helpers (all named members: no scratch) ======
struct G1P { uint4 x0, x1, x2, x3; float4 g0, g1, u0, u1; };

__device__ __forceinline__ void g1_load(G1P& P,
        const u16* xr0, const u16* xr1, const u16* xr2, const u16* xr3,
        const float* wg, const float* wu, int K0) {
    P.x0 = *(const uint4*)(xr0 + K0);
    P.x1 = *(const uint4*)(xr1 + K0);
    P.x2 = *(const uint4*)(xr2 + K0);
    P.x3 = *(const uint4*)(xr3 + K0);
    const float4* gp = (const float4*)(wg + K0);
    P.g0 = gp[0]; P.g1 = gp[1];
    const float4* up = (const float4*)(wu + K0);
    P.u0 = up[0]; P.u1 = up[1];
}

__device__ __forceinline__ void g1_write(u16* Xsb, u16* Gsb, u16* Usb,
                                         const G1P& P, int srow, int lc8) {
    *(uint4*)(Xsb + swz(srow,      lc8) * 8) = P.x0;
    *(uint4*)(Xsb + swz(srow + 32, lc8) * 8) = P.x1;
    *(uint4*)(Xsb + swz(srow + 64, lc8) * 8) = P.x2;
    *(uint4*)(Xsb + swz(srow + 96, lc8) * 8) = P.x3;
    *(uint4*)(Gsb + swz(srow, lc8) * 8) = cvt8f(P.g0, P.g1);
    *(uint4*)(Usb + swz(srow, lc8) * 8) = cvt8f(P.u0, P.u1);
}

__device__ __forceinline__ void g1_mfma(const u16* Xsb, const u16* Gsb, const u16* Usb,
                                        int wm, int lr, int lq,
                                        f32x4 (&ag)[2][2], f32x4 (&au)[2][2]) {
#pragma unroll
    for (int kk = 0; kk < 2; ++kk) {
        const int k8 = kk * 4 + lq;
        const bf16x8 af0 = *(const bf16x8*)(Xsb + swz(wm + lr,      k8) * 8);
        const bf16x8 af1 = *(const bf16x8*)(Xsb + swz(wm + 16 + lr, k8) * 8);
        const bf16x8 bg0 = *(const bf16x8*)(Gsb + swz(lr,      k8) * 8);
        const bf16x8 bg1 = *(const bf16x8*)(Gsb + swz(16 + lr, k8) * 8);
        const bf16x8 bu0 = *(const bf16x8*)(Usb + swz(lr,      k8) * 8);
        const bf16x8 bu1 = *(const bf16x8*)(Usb + swz(16 + lr, k8) * 8);
        ag[0][0] = mfma16(af0, bg0, ag[0][0]);
        ag[0][1] = mfma16(af0, bg1, ag[0][1]);
        ag[1][0] = mfma16(af1, bg0, ag[1][0]);
        ag[1][1] = mfma16(af1, bg1, ag[1][1]);
        au[0][0] = mfma16(af0, bu0, au[0][0]);
        au[0][1] = mfma16(af0, bu1, au[0][1]);
        au[1][0] = mfma16(af1, bu0, au[1][0]);
        au[1][1] = mfma16(af1, bu1, au[1][1]);
    }
}

// ---------------- GEMM1: gate/up + SwiGLU -> H (slot-ordered, bf16) ----------------
// block: 128 slots x 32 inter-cols; double-buffered LDS, 1 barrier/k-tile,
// 2-deep register prefetch: loads for tile t+2 issue right after tile t's
// barrier and are consumed one full iteration later.
__global__ __launch_bounds__(256, 3) void gemm1_kernel(
    const u16* __restrict__ Xb,    // [TOKENS, HIDDEN] bf16
    const float* __restrict__ Wg,  // [NEXP, INTER, HIDDEN] fp32
    const float* __restrict__ Wu,  // [NEXP, INTER, HIDDEN] fp32
    const int* __restrict__ meta, const int* __restrict__ bucket,
    u16* __restrict__ Hbuf)        // [NA, INTER] bf16, slot-ordered
{
    const int ty = blockIdx.y;
    if (ty >= meta[17]) return;
    const int e    = meta[32 + ty];
    const int m0   = meta[96 + ty];
    const int j0   = blockIdx.x * 32;
    const int base = meta[e];
    const int ne   = meta[e + 1] - base;

    __shared__ u16 Xs[2][MTILE * 64];  // 2 x 16 KB
    __shared__ u16 Gs[2][32 * 64];     // 2 x 4 KB
    __shared__ u16 Us[2][32 * 64];     // 2 x 4 KB   -> 48 KB total

    const int tid  = threadIdx.x;
    const int lane = tid & 63;
    const int wm   = (tid >> 6) * 32;
    const int lr   = lane & 15;
    const int lq   = lane >> 4;
    const int srow = tid >> 3;    // 0..31 staging row
    const int lc8  = tid & 7;     // 0..7  staging 16B chunk

    int t0, t1, t2, t3;
    {
        int s0 = m0 + srow;       s0 = s0 < ne ? s0 : ne - 1;
        int s1 = m0 + srow + 32;  s1 = s1 < ne ? s1 : ne - 1;
        int s2 = m0 + srow + 64;  s2 = s2 < ne ? s2 : ne - 1;
        int s3 = m0 + srow + 96;  s3 = s3 < ne ? s3 : ne - 1;
        t0 = bucket[base + s0] >> 1;
        t1 = bucket[base + s1] >> 1;
        t2 = bucket[base + s2] >> 1;
        t3 = bucket[base + s3] >> 1;
    }
    const u16* xr0 = Xb + (size_t)t0 * HIDDEN + lc8 * 8;
    const u16* xr1 = Xb + (size_t)t1 * HIDDEN + lc8 * 8;
    const u16* xr2 = Xb + (size_t)t2 * HIDDEN + lc8 * 8;
    const u16* xr3 = Xb + (size_t)t3 * HIDDEN + lc8 * 8;
    const float* wg = Wg + ((size_t)e * INTER + j0 + srow) * HIDDEN + lc8 * 8;
    const float* wu = Wu + ((size_t)e * INTER + j0 + srow) * HIDDEN + lc8 * 8;

    f32x4 ag[2][2] = {};
    f32x4 au[2][2] = {};

    G1P pA, pB;
    g1_load(pA, xr0, xr1, xr2, xr3, wg, wu, 0);
    g1_load(pB, xr0, xr1, xr2, xr3, wg, wu, 64);

    for (int k0 = 0; k0 < HIDDEN; k0 += 128) {
        g1_write(Xs[0], Gs[0], Us[0], pA, srow, lc8);
        __syncthreads();
        if (k0 + 128 < HIDDEN) g1_load(pA, xr0, xr1, xr2, xr3, wg, wu, k0 + 128);
        g1_mfma(Xs[0], Gs[0], Us[0], wm, lr, lq, ag, au);

        g1_write(Xs[1], Gs[1], Us[1], pB, srow, lc8);
        __syncthreads();
        if (k0 + 192 < HIDDEN) g1_load(pB, xr0, xr1, xr2, xr3, wg, wu, k0 + 192);
        g1_mfma(Xs[1], Gs[1], Us[1], wm, lr, lq, ag, au);
    }

    // epilogue: h = silu(g)*u ; C layout col=lane&15, row=lq*4+r
#pragma unroll
    for (int i = 0; i < 2; ++i)
#pragma unroll
        for (int r = 0; r < 4; ++r) {
            const int slot = m0 + wm + i * 16 + lq * 4 + r;
            if (slot < ne) {
#pragma unroll
                for (int j = 0; j < 2; ++j) {
                    const float g = ag[i][j][r];
                    const float u = au[i][j][r];
                    const float h = (g / (1.f + __expf(-g))) * u;
                    Hbuf[(size_t)(base + slot) * INTER + j0 + j * 16 + lr] = f2bf(h);
                }
            }
        }
}

// ================= GEMM2 pipeline helpers ======================================
struct G2P { uint4 h0, h1, h2, h3; float4 d0, d1; };

__device__ __forceinline__ void g2_load(G2P& P,
        const u16* hr0, const u16* hr1, const u16* hr2, const u16* hr3,
        const float* wd, int K0) {
    P.h0 = *(const uint4*)(hr0 + K0);
    P.h1 = *(const uint4*)(hr1 + K0);
    P.h2 = *(const uint4*)(hr2 + K0);
    P.h3 = *(const uint4*)(hr3 + K0);
    const float4* dp = (const float4*)(wd + K0);
    P.d0 = dp[0]; P.d1 = dp[1];
}

__device__ __forceinline__ void g2_write(u16* Hsb, u16* Dsb,
                                         const G2P& P, int srow, int lc8) {
    *(uint4*)(Hsb + swz(srow,      lc8) * 8) = P.h0;
    *(uint4*)(Hsb + swz(srow + 32, lc8) * 8) = P.h1;
    *(uint4*)(Hsb + swz(srow + 64, lc8) * 8) = P.h2;
    *(uint4*)(Hsb + swz(srow + 96, lc8) * 8) = P.h3;
    *(uint4*)(Dsb + swz(srow, lc8) * 8) = cvt8f(P.d0, P.d1);
}

__device__ __forceinline__ void g2_mfma(const u16* Hsb, const u16* Dsb,
                                        int wm, int lr, int lq, f32x4 (&ac)[2][2]) {
#pragma unroll
    for (int kk = 0; kk < 2; ++kk) {
        const int k8 = kk * 4 + lq;
        const bf16x8 af0 = *(const bf16x8*)(Hsb + swz(wm + lr,      k8) * 8);
        const bf16x8 af1 = *(const bf16x8*)(Hsb + swz(wm + 16 + lr, k8) * 8);
        const bf16x8 bd0 = *(const bf16x8*)(Dsb + swz(lr,      k8) * 8);
        const bf16x8 bd1 = *(const bf16x8*)(Dsb + swz(16 + lr, k8) * 8);
        ac[0][0] = mfma16(af0, bd0, ac[0][0]);
        ac[0][1] = mfma16(af0, bd1, ac[0][1]);
        ac[1][0] = mfma16(af1, bd0, ac[1][0]);
        ac[1][1] = mfma16(af1, bd1, ac[1][1]);
    }
}

// ---------------- GEMM2: down-proj -> weighted atomicAdd into out ----------------
// block: 128 slots x 32 hidden-cols; same dbuf + 2-deep register prefetch.
__global__ __launch_bounds__(256, 3) void gemm2_kernel(
    const u16* __restrict__ Hbuf,   // [NA, INTER] bf16, slot-ordered
    const float* __restrict__ Wd,   // [NEXP, HIDDEN, INTER] fp32
    const float* __restrict__ tkw,  // [TOKENS, 2] fp32
    const int* __restrict__ meta, const int* __restrict__ bucket,
    float* __restrict__ out)        // [TOKENS, HIDDEN] fp32, pre-zeroed
{
    const int ty = blockIdx.y;
    if (ty >= meta[17]) return;
    const int e    = meta[32 + ty];
    const int m0   = meta[96 + ty];
    const int n0   = blockIdx.x * 32;
    const int base = meta[e];
    const int ne   = meta[e + 1] - base;

    __shared__ u16 Hs[2][MTILE * 64];  // 2 x 16 KB
    __shared__ u16 Ds[2][32 * 64];     // 2 x 4 KB   -> 40 KB total

    const int tid  = threadIdx.x;
    const int lane = tid & 63;
    const int wm   = (tid >> 6) * 32;
    const int lr   = lane & 15;
    const int lq   = lane >> 4;
    const int srow = tid >> 3;
    const int lc8  = tid & 7;

    int s0 = m0 + srow;       s0 = s0 < ne ? s0 : ne - 1;
    int s1 = m0 + srow + 32;  s1 = s1 < ne ? s1 : ne - 1;
    int s2 = m0 + srow + 64;  s2 = s2 < ne ? s2 : ne - 1;
    int s3 = m0 + srow + 96;  s3 = s3 < ne ? s3 : ne - 1;
    const u16* hr0 = Hbuf + (size_t)(base + s0) * INTER + lc8 * 8;
    const u16* hr1 = Hbuf + (size_t)(base + s1) * INTER + lc8 * 8;
    const u16* hr2 = Hbuf + (size_t)(base + s2) * INTER + lc8 * 8;
    const u16* hr3 = Hbuf + (size_t)(base + s3) * INTER + lc8 * 8;
    const float* wd = Wd + ((size_t)e * HIDDEN + n0 + srow) * INTER + lc8 * 8;

    f32x4 ac[2][2] = {};

    G2P pA, pB;
    g2_load(pA, hr0, hr1, hr2, hr3, wd, 0);
    g2_load(pB, hr0, hr1, hr2, hr3, wd, 64);

    for (int k0 = 0; k0 < INTER; k0 += 128) {
        g2_write(Hs[0], Ds[0], pA, srow, lc8);
        __syncthreads();
        if (k0 + 128 < INTER) g2_load(pA, hr0, hr1, hr2, hr3, wd, k0 + 128);
        g2_mfma(Hs[0], Ds[0], wm, lr, lq, ac);

        g2_write(Hs[1], Ds[1], pB, srow, lc8);
        __syncthreads();
        if (k0 + 192 < INTER) g2_load(pB, hr0, hr1, hr2, hr3, wd, k0 + 192);
        g2_mfma(Hs[1], Ds[1], wm, lr, lq, ac);
    }

#pragma unroll
    for (int i = 0; i < 2; ++i)
#pragma unroll
        for (int r = 0; r < 4; ++r) {
            const int slot = m0 + wm + i * 16 + lq * 4 + r;
            if (slot < ne) {
                const int a = bucket[base + slot];
                const int t = a >> 1;
                const float w = tkw[a];
#pragma unroll
                for (int j = 0; j < 2; ++j)
                    atomicAdd(out + (size_t)t * HIDDEN + n0 + j * 16 + lr, w * ac[i][j][r]);
            }
        }
}

extern "C" void kernel_launch(void* const* d_in, const int* in_sizes, int n_in,
                              void* d_out, int out_size, void* d_ws, size_t ws_size,
                              hipStream_t stream) {
    const float* X   = (const float*)d_in[0];
    const int*   idx = (const int*)d_in[1];
    const float* tkw = (const float*)d_in[2];
    const float* Wg  = (const float*)d_in[3];
    const float* Wu  = (const float*)d_in[4];
    const float* Wd  = (const float*)d_in[5];
    float* out = (float*)d_out;

    char* ws = (char*)d_ws;
    int* meta   = (int*)ws;                     // off[0..16], ntiles[17], tileE[32..], tileM0[96..]
    int* bucket = (int*)(ws + 1024);            // 4096 ints
    u16* Xb     = (u16*)(ws + 32768);           // 8.39 MB
    u16* Hbuf   = (u16*)(ws + 32768 + (size_t)TOKENS * HIDDEN * 2);  // 6.29 MB

    hipMemsetAsync(out, 0, (size_t)TOKENS * HIDDEN * sizeof(float), stream);
    xcvt_kernel<<<TOKENS * HIDDEN / 8 / 256, 256, 0, stream>>>(X, Xb);
    route_kernel<<<1, 256, 0, stream>>>(idx, meta, bucket);
    dim3 g1(INTER / 32, MAXT);
    gemm1_kernel<<<g1, 256, 0, stream>>>(Xb, Wg, Wu, meta, bucket, Hbuf);
    dim3 g2(HIDDEN / 32, MAXT);
    gemm2_kernel<<<g2, 256, 0, stream>>>(Hbuf, Wd, tkw, meta, bucket, out);
}

// Round 5
// 391.235 us; speedup vs baseline: 1.8033x; 1.8033x over previous
//
#include <hip/hip_runtime.h>

#define TOKENS 2048
#define HIDDEN 2048
#define INTER  768
#define NEXP   16
#define NA     (TOKENS * 2)
#define MTILE  128
#define MAXT   64

typedef unsigned int   uint32;
typedef unsigned short u16;
typedef __bf16 bf16x8 __attribute__((ext_vector_type(8)));
typedef float  f32x4  __attribute__((ext_vector_type(4)));

__device__ __forceinline__ u16 f2bf(float f) {
    union { float f; uint32 u; } v; v.f = f;
    return (u16)((v.u + 0x7fffu + ((v.u >> 16) & 1u)) >> 16);
}
// fast pack of two fp32 -> two bf16 (round-half-away; plenty for 2% threshold)
__device__ __forceinline__ uint32 pk2(float a, float b) {
    union { float f; uint32 u; } x, y; x.f = a; y.f = b;
    return ((x.u + 0x8000u) >> 16) | ((y.u + 0x8000u) & 0xffff0000u);
}
__device__ __forceinline__ uint4 cvt8f(float4 a, float4 b) {
    uint4 o;
    o.x = pk2(a.x, a.y); o.y = pk2(a.z, a.w);
    o.z = pk2(b.x, b.y); o.w = pk2(b.z, b.w);
    return o;
}
// 16B-unit index into a row-major (rowstride 128 bf16 = 16 chunks) LDS tile,
// XOR-swizzled: row r, logical chunk c stored at r*16 + (c ^ (r&15)).
__device__ __forceinline__ int swz16(int row, int c) { return row * 16 + (c ^ (row & 15)); }

__device__ __forceinline__ f32x4 mfma16(bf16x8 a, bf16x8 b, f32x4 c) {
    return __builtin_amdgcn_mfma_f32_16x16x32_bf16(a, b, c, 0, 0, 0);
}

// ---------------- X: fp32 -> bf16 once ----------------
__global__ void xcvt_kernel(const float* __restrict__ X, u16* __restrict__ Xb) {
    const int gid = blockIdx.x * 256 + threadIdx.x;
    const float4* s = (const float4*)X + (size_t)gid * 2;
    ((uint4*)Xb)[gid] = cvt8f(s[0], s[1]);
}

// ---------------- routing: bucket assignments, emit m-tile list ----------------
__global__ void route_kernel(const int* __restrict__ idx, int* __restrict__ meta,
                             int* __restrict__ bucket) {
    __shared__ int scnt[NEXP];
    __shared__ int soff[NEXP + 1];
    __shared__ int sfill[NEXP];
    __shared__ int sflag;
    const int tid = threadIdx.x;
    if (tid < NEXP) { scnt[tid] = 0; sfill[tid] = 0; }
    if (tid == 0) sflag = 0;
    __syncthreads();
    // int64-vs-int32 probe: int64 buffer has all-zero odd words
    int any = 0;
    for (int a = tid; a < NA / 2; a += 256) any |= idx[2 * a + 1];
    if (any) atomicOr(&sflag, 1);
    __syncthreads();
    const int stride = sflag ? 1 : 2;
    for (int a = tid; a < NA; a += 256) atomicAdd(&scnt[idx[a * stride]], 1);
    __syncthreads();
    if (tid == 0) {
        int s = 0;
        for (int e = 0; e < NEXP; ++e) { soff[e] = s; s += scnt[e]; }
        soff[NEXP] = s;
        int nt = 0;
        for (int e = 0; e < NEXP; ++e) {
            const int ne = soff[e + 1] - soff[e];
            for (int m0 = 0; m0 < ne; m0 += MTILE) {
                meta[32 + nt] = e;      // tile expert
                meta[96 + nt] = m0;     // tile m0
                ++nt;
            }
        }
        meta[17] = nt;
    }
    __syncthreads();
    for (int a = tid; a < NA; a += 256) {
        int e = idx[a * stride];
        int slot = atomicAdd(&sfill[e], 1);
        bucket[soff[e] + slot] = a;   // assignment id; token = a>>1
    }
    if (tid <= NEXP) meta[tid] = soff[tid];
}

// ---------------- GEMM1: gate/up + SwiGLU -> H (slot-ordered, bf16) ----------------
// block: 128 slots x 64 inter-cols, BK=128 (64 KB LDS, 16 k-iters).
// R0-proven codegen shape: straight load->cvt->ds_write staging, transient regs
// only, zero cross-iteration register state (R2/R3 showed prefetch structs are
// demoted to scratch). BK=128 doubles bytes+MFMA per barrier period vs R0.
__global__ __launch_bounds__(256, 2) void gemm1_kernel(
    const u16* __restrict__ Xb,    // [TOKENS, HIDDEN] bf16
    const float* __restrict__ Wg,  // [NEXP, INTER, HIDDEN] fp32
    const float* __restrict__ Wu,  // [NEXP, INTER, HIDDEN] fp32
    const int* __restrict__ meta, const int* __restrict__ bucket,
    u16* __restrict__ Hbuf)        // [NA, INTER] bf16, slot-ordered
{
    const int ty = blockIdx.y;
    if (ty >= meta[17]) return;
    const int e    = meta[32 + ty];
    const int m0   = meta[96 + ty];
    const int j0   = blockIdx.x * 64;
    const int base = meta[e];
    const int ne   = meta[e + 1] - base;

    __shared__ u16 Xs[MTILE * 128];  // 32 KB
    __shared__ u16 Gs[64 * 128];     // 16 KB
    __shared__ u16 Us[64 * 128];     // 16 KB  -> 64 KB total

    const int tid  = threadIdx.x;
    const int lane = tid & 63;
    const int wm   = (tid >> 6) * 32;
    const int lr   = lane & 15;
    const int lq   = lane >> 4;
    const int srow = tid >> 3;    // 0..31 staging row
    const int c8   = tid & 7;     // 0..7  staging chunk base

    int tok[4];
#pragma unroll
    for (int p = 0; p < 4; ++p) {
        int slot = m0 + srow + p * 32;
        slot = slot < ne ? slot : ne - 1;
        tok[p] = bucket[base + slot] >> 1;
    }

    f32x4 ag[2][4] = {};
    f32x4 au[2][4] = {};
    for (int k0 = 0; k0 < HIDDEN; k0 += 128) {
        __syncthreads();
        // X: rows srow+32p, chunks c8 and c8+8 (256 B/row, 16 chunks)
#pragma unroll
        for (int p = 0; p < 4; ++p) {
            const int row = srow + p * 32;
            const u16* xr = Xb + (size_t)tok[p] * HIDDEN + k0;
            const uint4 a = *(const uint4*)(xr + c8 * 8);
            const uint4 b = *(const uint4*)(xr + (c8 + 8) * 8);
            *(uint4*)(Xs + swz16(row, c8) * 8)     = a;
            *(uint4*)(Xs + swz16(row, c8 + 8) * 8) = b;
        }
        // Wg/Wu: rows srow+32p (p<2), each thread covers chunks 2*c8, 2*c8+1
#pragma unroll
        for (int p = 0; p < 2; ++p) {
            const int row = srow + p * 32;
            const size_t wr = ((size_t)e * INTER + j0 + row) * HIDDEN + k0 + c8 * 16;
            const float4* gp = (const float4*)(Wg + wr);
            *(uint4*)(Gs + swz16(row, 2 * c8) * 8)     = cvt8f(gp[0], gp[1]);
            *(uint4*)(Gs + swz16(row, 2 * c8 + 1) * 8) = cvt8f(gp[2], gp[3]);
            const float4* up = (const float4*)(Wu + wr);
            *(uint4*)(Us + swz16(row, 2 * c8) * 8)     = cvt8f(up[0], up[1]);
            *(uint4*)(Us + swz16(row, 2 * c8 + 1) * 8) = cvt8f(up[2], up[3]);
        }
        __syncthreads();
#pragma unroll
        for (int kk = 0; kk < 4; ++kk) {
            const int k8 = kk * 4 + lq;
            bf16x8 af[2], bg[4], bu[4];
#pragma unroll
            for (int i = 0; i < 2; ++i)
                af[i] = *(const bf16x8*)(Xs + swz16(wm + i * 16 + lr, k8) * 8);
#pragma unroll
            for (int j = 0; j < 4; ++j) {
                bg[j] = *(const bf16x8*)(Gs + swz16(j * 16 + lr, k8) * 8);
                bu[j] = *(const bf16x8*)(Us + swz16(j * 16 + lr, k8) * 8);
            }
#pragma unroll
            for (int i = 0; i < 2; ++i)
#pragma unroll
                for (int j = 0; j < 4; ++j) {
                    ag[i][j] = mfma16(af[i], bg[j], ag[i][j]);
                    au[i][j] = mfma16(af[i], bu[j], au[i][j]);
                }
        }
    }
    // epilogue: h = silu(g)*u ; C layout col=lane&15, row=lq*4+r
#pragma unroll
    for (int i = 0; i < 2; ++i)
#pragma unroll
        for (int r = 0; r < 4; ++r) {
            const int slot = m0 + wm + i * 16 + lq * 4 + r;
            if (slot < ne) {
#pragma unroll
                for (int j = 0; j < 4; ++j) {
                    const float g = ag[i][j][r];
                    const float u = au[i][j][r];
                    const float h = (g / (1.f + __expf(-g))) * u;
                    Hbuf[(size_t)(base + slot) * INTER + j0 + j * 16 + lr] = f2bf(h);
                }
            }
        }
}

// ---------------- GEMM2: down-proj -> weighted atomicAdd into out ----------------
// block: 128 slots x 64 hidden-cols, BK=128 (48 KB LDS, 6 k-iters).
__global__ __launch_bounds__(256, 3) void gemm2_kernel(
    const u16* __restrict__ Hbuf,   // [NA, INTER] bf16, slot-ordered
    const float* __restrict__ Wd,   // [NEXP, HIDDEN, INTER] fp32
    const float* __restrict__ tkw,  // [TOKENS, 2] fp32
    const int* __restrict__ meta, const int* __restrict__ bucket,
    float* __restrict__ out)        // [TOKENS, HIDDEN] fp32, pre-zeroed
{
    const int ty = blockIdx.y;
    if (ty >= meta[17]) return;
    const int e    = meta[32 + ty];
    const int m0   = meta[96 + ty];
    const int n0   = blockIdx.x * 64;
    const int base = meta[e];
    const int ne   = meta[e + 1] - base;

    __shared__ u16 Hs[MTILE * 128];  // 32 KB
    __shared__ u16 Ds[64 * 128];     // 16 KB  -> 48 KB total

    const int tid  = threadIdx.x;
    const int lane = tid & 63;
    const int wm   = (tid >> 6) * 32;
    const int lr   = lane & 15;
    const int lq   = lane >> 4;
    const int srow = tid >> 3;
    const int c8   = tid & 7;

    int sl[4];
#pragma unroll
    for (int p = 0; p < 4; ++p) {
        int slot = m0 + srow + p * 32;
        sl[p] = slot < ne ? slot : ne - 1;
    }

    f32x4 ac[2][4] = {};
    for (int k0 = 0; k0 < INTER; k0 += 128) {
        __syncthreads();
#pragma unroll
        for (int p = 0; p < 4; ++p) {
            const int row = srow + p * 32;
            const u16* hr = Hbuf + (size_t)(base + sl[p]) * INTER + k0;
            const uint4 a = *(const uint4*)(hr + c8 * 8);
            const uint4 b = *(const uint4*)(hr + (c8 + 8) * 8);
            *(uint4*)(Hs + swz16(row, c8) * 8)     = a;
            *(uint4*)(Hs + swz16(row, c8 + 8) * 8) = b;
        }
#pragma unroll
        for (int p = 0; p < 2; ++p) {
            const int row = srow + p * 32;
            const float4* dp = (const float4*)(Wd + ((size_t)e * HIDDEN + n0 + row) * INTER + k0 + c8 * 16);
            *(uint4*)(Ds + swz16(row, 2 * c8) * 8)     = cvt8f(dp[0], dp[1]);
            *(uint4*)(Ds + swz16(row, 2 * c8 + 1) * 8) = cvt8f(dp[2], dp[3]);
        }
        __syncthreads();
#pragma unroll
        for (int kk = 0; kk < 4; ++kk) {
            const int k8 = kk * 4 + lq;
            bf16x8 af[2], bd[4];
#pragma unroll
            for (int i = 0; i < 2; ++i)
                af[i] = *(const bf16x8*)(Hs + swz16(wm + i * 16 + lr, k8) * 8);
#pragma unroll
            for (int j = 0; j < 4; ++j)
                bd[j] = *(const bf16x8*)(Ds + swz16(j * 16 + lr, k8) * 8);
#pragma unroll
            for (int i = 0; i < 2; ++i)
#pragma unroll
                for (int j = 0; j < 4; ++j)
                    ac[i][j] = mfma16(af[i], bd[j], ac[i][j]);
        }
    }
#pragma unroll
    for (int i = 0; i < 2; ++i)
#pragma unroll
        for (int r = 0; r < 4; ++r) {
            const int slot = m0 + wm + i * 16 + lq * 4 + r;
            if (slot < ne) {
                const int a = bucket[base + slot];
                const int t = a >> 1;
                const float w = tkw[a];
#pragma unroll
                for (int j = 0; j < 4; ++j)
                    atomicAdd(out + (size_t)t * HIDDEN + n0 + j * 16 + lr, w * ac[i][j][r]);
            }
        }
}

extern "C" void kernel_launch(void* const* d_in, const int* in_sizes, int n_in,
                              void* d_out, int out_size, void* d_ws, size_t ws_size,
                              hipStream_t stream) {
    const float* X   = (const float*)d_in[0];
    const int*   idx = (const int*)d_in[1];
    const float* tkw = (const float*)d_in[2];
    const float* Wg  = (const float*)d_in[3];
    const float* Wu  = (const float*)d_in[4];
    const float* Wd  = (const float*)d_in[5];
    float* out = (float*)d_out;

    char* ws = (char*)d_ws;
    int* meta   = (int*)ws;                     // off[0..16], ntiles[17], tileE[32..], tileM0[96..]
    int* bucket = (int*)(ws + 1024);            // 4096 ints
    u16* Xb     = (u16*)(ws + 32768);           // 8.39 MB
    u16* Hbuf   = (u16*)(ws + 32768 + (size_t)TOKENS * HIDDEN * 2);  // 6.29 MB

    hipMemsetAsync(out, 0, (size_t)TOKENS * HIDDEN * sizeof(float), stream);
    xcvt_kernel<<<TOKENS * HIDDEN / 8 / 256, 256, 0, stream>>>(X, Xb);
    route_kernel<<<1, 256, 0, stream>>>(idx, meta, bucket);
    dim3 g1(INTER / 64, MAXT);
    gemm1_kernel<<<g1, 256, 0, stream>>>(Xb, Wg, Wu, meta, bucket, Hbuf);
    dim3 g2(HIDDEN / 64, MAXT);
    gemm2_kernel<<<g2, 256, 0, stream>>>(Hbuf, Wd, tkw, meta, bucket, out);
}